// Round 1
// baseline (221.126 us; speedup 1.0000x reference)
//
#include <hip/hip_runtime.h>
#include <hip/hip_bf16.h>
#include <stdint.h>

// Problem constants (fixed shapes from reference: B=4096, D=256, N=2B)
#define NROWS 8192
#define DDIM  256
#define BM    128
#define BN    128
#define BK    32
#define L2E   1.44269504088896340736f

typedef __attribute__((ext_vector_type(8))) short short8;
typedef __attribute__((ext_vector_type(4))) float f32x4;

typedef const __attribute__((address_space(1))) uint32_t glb_u32;
typedef __attribute__((address_space(3))) uint32_t lds_u32;

__device__ __forceinline__ void load_lds16(const unsigned short* g, unsigned short* l) {
  // 16B per lane, LDS dest = wave-uniform base + lane*16 (HW scatter)
  __builtin_amdgcn_global_load_lds((glb_u32*)g, (lds_u32*)l, 16, 0, 0);
}

__device__ __forceinline__ unsigned short f2bf(float x) {
  __hip_bfloat16 h = __float2bfloat16(x);
  return *reinterpret_cast<unsigned short*>(&h);
}

// Kernel 1: build bf16 concat(f), inv norms (fp32), int labels, zero S arrays.
__global__ void __launch_bounds__(256)
milnce_prep(const float* __restrict__ feat, const float* __restrict__ pos,
            const int* __restrict__ labels, unsigned short* __restrict__ fb,
            float* __restrict__ inv_w, int* __restrict__ lab,
            float* __restrict__ S_all, float* __restrict__ S_pos) {
  const int wave = threadIdx.x >> 6;
  const int lane = threadIdx.x & 63;
  const int row  = blockIdx.x * 4 + wave;   // grid 2048 blocks -> 8192 rows

  const float* src = (row < 4096) ? (feat + (size_t)row * DDIM)
                                  : (pos + (size_t)(row - 4096) * DDIM);
  float4 v = ((const float4*)src)[lane];    // 4 contiguous fp32 per lane

  ushort4 o;
  o.x = f2bf(v.x); o.y = f2bf(v.y); o.z = f2bf(v.z); o.w = f2bf(v.w);
  ((ushort4*)(fb + (size_t)row * DDIM))[lane] = o;

  float ss = v.x*v.x + v.y*v.y + v.z*v.z + v.w*v.w;
  #pragma unroll
  for (int m = 1; m < 64; m <<= 1) ss += __shfl_xor(ss, m, 64);
  if (lane == 0) inv_w[row] = 1.0f / sqrtf(ss);

  const int tid = blockIdx.x * 256 + threadIdx.x;
  if (tid < NROWS) {
    lab[tid]   = labels[tid & 4095];  // concat duplicates labels
    S_all[tid] = 0.0f;
    S_pos[tid] = 0.0f;
  }
}

// Kernel 2: fused f@f^T (bf16 MFMA) + exp((z-10)) masked row-sums.
// m97 structure: 128x128 tile, 4 waves (2x2 of 64x64), 16x16x32 bf16 MFMA,
// global_load_lds width=16 staging, BK=32, K=256 -> 8 iters.
__global__ void __launch_bounds__(256)
milnce_gemm(const unsigned short* __restrict__ fb, const float* __restrict__ inv_w,
            const int* __restrict__ lab, float* __restrict__ S_all,
            float* __restrict__ S_pos) {
  __shared__ unsigned short ldsA[BM * BK];  // 8 KB
  __shared__ unsigned short ldsB[BN * BK];  // 8 KB

  const int tid  = threadIdx.x;
  const int wave = tid >> 6;
  const int lane = tid & 63;
  const int quad = lane >> 4;
  const int l15  = lane & 15;
  const int wm   = wave >> 1;   // 2x2 wave grid over 128x128
  const int wn   = wave & 1;
  const int rowBase = blockIdx.y * BM;
  const int colBase = blockIdx.x * BN;

  f32x4 acc[4][4];
  #pragma unroll
  for (int i = 0; i < 4; ++i)
    #pragma unroll
    for (int j = 0; j < 4; ++j) acc[i][j] = (f32x4){0.f, 0.f, 0.f, 0.f};

  // staging chunk ids: chunk c in [0,512), covers tile row c>>2, k-slice (c&3)*8
  const int c0 = wave * 64 + lane;       // load 0
  const int c1 = c0 + 256;               // load 1
  const unsigned short* gA0 = fb + (size_t)(rowBase + (c0 >> 2)) * DDIM + (c0 & 3) * 8;
  const unsigned short* gA1 = fb + (size_t)(rowBase + (c1 >> 2)) * DDIM + (c1 & 3) * 8;
  const unsigned short* gB0 = fb + (size_t)(colBase + (c0 >> 2)) * DDIM + (c0 & 3) * 8;
  const unsigned short* gB1 = fb + (size_t)(colBase + (c1 >> 2)) * DDIM + (c1 & 3) * 8;
  unsigned short* lA0 = ldsA + (size_t)(wave * 64) * 8;          // wave-uniform bases
  unsigned short* lA1 = ldsA + (size_t)(wave * 64 + 256) * 8;
  unsigned short* lB0 = ldsB + (size_t)(wave * 64) * 8;
  unsigned short* lB1 = ldsB + (size_t)(wave * 64 + 256) * 8;

  #pragma unroll
  for (int kt = 0; kt < DDIM / BK; ++kt) {
    const int ko = kt * BK;
    __syncthreads();                       // protect LDS reuse
    load_lds16(gA0 + ko, lA0);
    load_lds16(gA1 + ko, lA1);
    load_lds16(gB0 + ko, lB0);
    load_lds16(gB1 + ko, lB1);
    __syncthreads();                       // drains vmcnt (compiler-inserted)

    short8 a[4], b[4];
    #pragma unroll
    for (int mi = 0; mi < 4; ++mi)
      a[mi] = *(const short8*)&ldsA[(wm * 64 + mi * 16 + l15) * BK + quad * 8];
    #pragma unroll
    for (int ni = 0; ni < 4; ++ni)
      b[ni] = *(const short8*)&ldsB[(wn * 64 + ni * 16 + l15) * BK + quad * 8];

    #pragma unroll
    for (int mi = 0; mi < 4; ++mi)
      #pragma unroll
      for (int ni = 0; ni < 4; ++ni)
        acc[mi][ni] = __builtin_amdgcn_mfma_f32_16x16x32_bf16(a[mi], b[ni], acc[mi][ni], 0, 0, 0);
  }

  // Epilogue. C/D layout (16x16x32): col = lane&15, row = quad*4 + reg.
  // z = dot * inv_wi * inv_wj * 10 ; e = exp2(z*L2E - 10*L2E) ; mask diag/labels.
  const float SHIFT = 10.0f * L2E;
  float cf[4]; int cl[4], colg[4];
  #pragma unroll
  for (int ni = 0; ni < 4; ++ni) {
    colg[ni] = colBase + wn * 64 + ni * 16 + l15;
    cf[ni]   = inv_w[colg[ni]] * (10.0f * L2E);
    cl[ni]   = lab[colg[ni]];
  }

  #pragma unroll
  for (int mi = 0; mi < 4; ++mi) {
    #pragma unroll
    for (int r = 0; r < 4; ++r) {
      const int rowg = rowBase + wm * 64 + mi * 16 + quad * 4 + r;
      const float rf = inv_w[rowg];
      const int   rl = lab[rowg];
      float sa = 0.f, sp = 0.f;
      #pragma unroll
      for (int ni = 0; ni < 4; ++ni) {
        float t = acc[mi][ni][r] * rf * cf[ni] - SHIFT;
        float e = exp2f(t);
        if (rowg == colg[ni]) e = 0.f;   // diagonal excluded from both sums
        sa += e;
        if (rl == cl[ni]) sp += e;       // same-label (diag already zeroed)
      }
      // reduce over the 16 columns held by this quad's 16 lanes
      sa += __shfl_xor(sa, 1); sa += __shfl_xor(sa, 2);
      sa += __shfl_xor(sa, 4); sa += __shfl_xor(sa, 8);
      sp += __shfl_xor(sp, 1); sp += __shfl_xor(sp, 2);
      sp += __shfl_xor(sp, 4); sp += __shfl_xor(sp, 8);
      if (l15 == mi * 4 + r) {           // one lane per quad commits this row
        atomicAdd(&S_all[rowg], sa);
        atomicAdd(&S_pos[rowg], sp);
      }
    }
  }
}

// Kernel 3: loss = sum_i log(S_all[i]) - log(S_pos[i])  (the +10 shifts cancel)
__global__ void __launch_bounds__(1024)
milnce_final(const float* __restrict__ S_all, const float* __restrict__ S_pos,
             float* __restrict__ out) {
  __shared__ float red[16];
  float s = 0.f;
  for (int i = threadIdx.x; i < NROWS; i += 1024)
    s += logf(S_all[i]) - logf(S_pos[i]);
  #pragma unroll
  for (int m = 1; m < 64; m <<= 1) s += __shfl_xor(s, m, 64);
  const int wave = threadIdx.x >> 6;
  if ((threadIdx.x & 63) == 0) red[wave] = s;
  __syncthreads();
  if (threadIdx.x == 0) {
    float t = 0.f;
    #pragma unroll
    for (int i = 0; i < 16; ++i) t += red[i];
    out[0] = t;
  }
}

extern "C" void kernel_launch(void* const* d_in, const int* in_sizes, int n_in,
                              void* d_out, int out_size, void* d_ws, size_t ws_size,
                              hipStream_t stream) {
  const float* feat   = (const float*)d_in[0];
  const float* pos    = (const float*)d_in[1];
  const int*   labels = (const int*)d_in[2];

  char* ws = (char*)d_ws;
  unsigned short* fb    = (unsigned short*)ws;                       // 4 MB bf16 concat
  float*          inv_w = (float*)(ws + 4u * 1024 * 1024);           // 32 KB
  int*            lab   = (int*)  (ws + 4u * 1024 * 1024 + 32 * 1024);
  float*          S_all = (float*)(ws + 4u * 1024 * 1024 + 64 * 1024);
  float*          S_pos = (float*)(ws + 4u * 1024 * 1024 + 96 * 1024);
  float*          out   = (float*)d_out;

  hipLaunchKernelGGL(milnce_prep, dim3(NROWS / 4), dim3(256), 0, stream,
                     feat, pos, labels, fb, inv_w, lab, S_all, S_pos);
  hipLaunchKernelGGL(milnce_gemm, dim3(NROWS / BN, NROWS / BM), dim3(256), 0, stream,
                     fb, inv_w, lab, S_all, S_pos);
  hipLaunchKernelGGL(milnce_final, dim3(1), dim3(1024), 0, stream,
                     S_all, S_pos, out);
}

// Round 2
// 131.062 us; speedup vs baseline: 1.6872x; 1.6872x over previous
//
#include <hip/hip_runtime.h>
#include <hip/hip_bf16.h>
#include <stdint.h>

// Problem constants (fixed shapes from reference: B=4096, D=256, N=2B)
#define NROWS 8192
#define DDIM  256
#define BM    128
#define BN    128
#define BK    32
#define L2E   1.44269504088896340736f

typedef __attribute__((ext_vector_type(8))) short short8;
typedef __attribute__((ext_vector_type(4))) float f32x4;

typedef const __attribute__((address_space(1))) uint32_t glb_u32;
typedef __attribute__((address_space(3))) uint32_t lds_u32;

__device__ __forceinline__ void load_lds16(const unsigned short* g, unsigned short* l) {
  // 16B per lane, LDS dest = wave-uniform base + lane*16 (HW scatter)
  __builtin_amdgcn_global_load_lds((glb_u32*)g, (lds_u32*)l, 16, 0, 0);
}

__device__ __forceinline__ unsigned short f2bf(float x) {
  __hip_bfloat16 h = __float2bfloat16(x);
  return *reinterpret_cast<unsigned short*>(&h);
}

// Kernel 1: build bf16 concat(f), inv norms (fp32), int labels, zero S arrays.
__global__ void __launch_bounds__(256)
milnce_prep(const float* __restrict__ feat, const float* __restrict__ pos,
            const int* __restrict__ labels, unsigned short* __restrict__ fb,
            float* __restrict__ inv_w, int* __restrict__ lab,
            float* __restrict__ S_all, float* __restrict__ S_pos) {
  const int wave = threadIdx.x >> 6;
  const int lane = threadIdx.x & 63;
  const int row  = blockIdx.x * 4 + wave;   // grid 2048 blocks -> 8192 rows

  const float* src = (row < 4096) ? (feat + (size_t)row * DDIM)
                                  : (pos + (size_t)(row - 4096) * DDIM);
  float4 v = ((const float4*)src)[lane];    // 4 contiguous fp32 per lane

  ushort4 o;
  o.x = f2bf(v.x); o.y = f2bf(v.y); o.z = f2bf(v.z); o.w = f2bf(v.w);
  ((ushort4*)(fb + (size_t)row * DDIM))[lane] = o;

  float ss = v.x*v.x + v.y*v.y + v.z*v.z + v.w*v.w;
  #pragma unroll
  for (int m = 1; m < 64; m <<= 1) ss += __shfl_xor(ss, m, 64);
  if (lane == 0) inv_w[row] = 1.0f / sqrtf(ss);

  const int tid = blockIdx.x * 256 + threadIdx.x;
  if (tid < NROWS) {
    lab[tid]   = labels[tid & 4095];  // concat duplicates labels
    S_all[tid] = 0.0f;
    S_pos[tid] = 0.0f;
  }
}

// Kernel 2: fused f@f^T (bf16 MFMA) + exp(z-10) masked COLUMN-sums.
// z is symmetric (f f^T, symmetric masks), so column sums == row sums; the
// column reduction in the 16x16x32 C-layout needs only 2 shfl (quads) instead
// of a 16-lane butterfly per row.
// LDS k-slices are XOR-swizzled so fragment reads spread over 8 bank-start
// positions (2-way aliasing = free) instead of 2 (8-way conflict).
__global__ void __launch_bounds__(256)
milnce_gemm(const unsigned short* __restrict__ fb, const float* __restrict__ inv_w,
            const int* __restrict__ lab, float* __restrict__ S_all,
            float* __restrict__ S_pos) {
  __shared__ unsigned short ldsA[BM * BK];  // 8 KB
  __shared__ unsigned short ldsB[BN * BK];  // 8 KB

  const int tid  = threadIdx.x;
  const int wave = tid >> 6;
  const int lane = tid & 63;
  const int quad = lane >> 4;
  const int l15  = lane & 15;
  const int wm   = wave >> 1;   // 2x2 wave grid over 128x128
  const int wn   = wave & 1;
  const int rowBase = blockIdx.y * BM;
  const int colBase = blockIdx.x * BN;

  f32x4 acc[4][4];
  #pragma unroll
  for (int i = 0; i < 4; ++i)
    #pragma unroll
    for (int j = 0; j < 4; ++j) acc[i][j] = (f32x4){0.f, 0.f, 0.f, 0.f};

  // Staging: slot s (0..511) is 16B at LDS offset s*16; row = s>>2.
  // Swizzle: slot s holds global k-slice gsl = (s&3) ^ ((s>>3)&3), so the
  // 4 lanes covering one row still fetch the same contiguous 64B (coalesced),
  // just permuted among themselves.
  const int s0 = wave * 64 + lane;       // load 0
  const int s1 = s0 + 256;               // load 1
  const int r0 = s0 >> 2, g0 = (s0 & 3) ^ ((s0 >> 3) & 3);
  const int r1 = s1 >> 2, g1 = (s1 & 3) ^ ((s1 >> 3) & 3);
  const unsigned short* gA0 = fb + (size_t)(rowBase + r0) * DDIM + g0 * 8;
  const unsigned short* gA1 = fb + (size_t)(rowBase + r1) * DDIM + g1 * 8;
  const unsigned short* gB0 = fb + (size_t)(colBase + r0) * DDIM + g0 * 8;
  const unsigned short* gB1 = fb + (size_t)(colBase + r1) * DDIM + g1 * 8;
  unsigned short* lA0 = ldsA + (size_t)(wave * 64) * 8;          // wave-uniform bases
  unsigned short* lA1 = ldsA + (size_t)(wave * 64 + 256) * 8;
  unsigned short* lB0 = ldsB + (size_t)(wave * 64) * 8;
  unsigned short* lB1 = ldsB + (size_t)(wave * 64 + 256) * 8;

  // Reader swizzle: for row r (r mod 16 == l15), global slice `quad` lives at
  // LDS slice xsl = quad ^ ((r>>1)&3) = quad ^ ((l15>>1)&3).
  const int xsl = quad ^ ((l15 >> 1) & 3);

  #pragma unroll
  for (int kt = 0; kt < DDIM / BK; ++kt) {
    const int ko = kt * BK;
    __syncthreads();                       // protect LDS reuse
    load_lds16(gA0 + ko, lA0);
    load_lds16(gA1 + ko, lA1);
    load_lds16(gB0 + ko, lB0);
    load_lds16(gB1 + ko, lB1);
    __syncthreads();                       // drains vmcnt (compiler-inserted)

    short8 a[4], b[4];
    #pragma unroll
    for (int mi = 0; mi < 4; ++mi)
      a[mi] = *(const short8*)&ldsA[(wm * 64 + mi * 16 + l15) * BK + xsl * 8];
    #pragma unroll
    for (int ni = 0; ni < 4; ++ni)
      b[ni] = *(const short8*)&ldsB[(wn * 64 + ni * 16 + l15) * BK + xsl * 8];

    #pragma unroll
    for (int mi = 0; mi < 4; ++mi)
      #pragma unroll
      for (int ni = 0; ni < 4; ++ni)
        acc[mi][ni] = __builtin_amdgcn_mfma_f32_16x16x32_bf16(a[mi], b[ni], acc[mi][ni], 0, 0, 0);
  }

  // Epilogue. C/D layout (16x16x32): col = lane&15, row = quad*4 + reg.
  // z = dot * inv_wi * inv_wj * 10 ; e = exp2(z*L2E - 10*L2E) ; mask diag/labels.
  // Accumulate COLUMN sums (== row sums by symmetry): in-register over (mi,r),
  // then 2 shfl across quads, then one atomic per column from quad-0 lanes.
  const float SHIFT = 10.0f * L2E;
  float cf[4]; int cl[4], colg[4];
  #pragma unroll
  for (int ni = 0; ni < 4; ++ni) {
    colg[ni] = colBase + wn * 64 + ni * 16 + l15;
    cf[ni]   = inv_w[colg[ni]] * (10.0f * L2E);
    cl[ni]   = lab[colg[ni]];
  }

  float ca[4] = {0.f, 0.f, 0.f, 0.f};
  float cp[4] = {0.f, 0.f, 0.f, 0.f};
  #pragma unroll
  for (int mi = 0; mi < 4; ++mi) {
    #pragma unroll
    for (int r = 0; r < 4; ++r) {
      const int rowg = rowBase + wm * 64 + mi * 16 + quad * 4 + r;
      const float rf = inv_w[rowg];
      const int   rl = lab[rowg];
      #pragma unroll
      for (int ni = 0; ni < 4; ++ni) {
        float e = exp2f(acc[mi][ni][r] * rf * cf[ni] - SHIFT);
        if (rowg == colg[ni]) e = 0.f;   // diagonal excluded from both sums
        ca[ni] += e;
        if (rl == cl[ni]) cp[ni] += e;   // same-label (diag already zeroed)
      }
    }
  }
  #pragma unroll
  for (int ni = 0; ni < 4; ++ni) {
    ca[ni] += __shfl_xor(ca[ni], 16, 64);
    ca[ni] += __shfl_xor(ca[ni], 32, 64);
    cp[ni] += __shfl_xor(cp[ni], 16, 64);
    cp[ni] += __shfl_xor(cp[ni], 32, 64);
  }
  if (quad == 0) {
    #pragma unroll
    for (int ni = 0; ni < 4; ++ni) {
      atomicAdd(&S_all[colg[ni]], ca[ni]);
      atomicAdd(&S_pos[colg[ni]], cp[ni]);
    }
  }
}

// Kernel 3: loss = sum_i log(S_all[i]) - log(S_pos[i])  (the +10 shifts cancel)
__global__ void __launch_bounds__(1024)
milnce_final(const float* __restrict__ S_all, const float* __restrict__ S_pos,
             float* __restrict__ out) {
  __shared__ float red[16];
  float s = 0.f;
  for (int i = threadIdx.x; i < NROWS; i += 1024)
    s += logf(S_all[i]) - logf(S_pos[i]);
  #pragma unroll
  for (int m = 1; m < 64; m <<= 1) s += __shfl_xor(s, m, 64);
  const int wave = threadIdx.x >> 6;
  if ((threadIdx.x & 63) == 0) red[wave] = s;
  __syncthreads();
  if (threadIdx.x == 0) {
    float t = 0.f;
    #pragma unroll
    for (int i = 0; i < 16; ++i) t += red[i];
    out[0] = t;
  }
}

extern "C" void kernel_launch(void* const* d_in, const int* in_sizes, int n_in,
                              void* d_out, int out_size, void* d_ws, size_t ws_size,
                              hipStream_t stream) {
  const float* feat   = (const float*)d_in[0];
  const float* pos    = (const float*)d_in[1];
  const int*   labels = (const int*)d_in[2];

  char* ws = (char*)d_ws;
  unsigned short* fb    = (unsigned short*)ws;                       // 4 MB bf16 concat
  float*          inv_w = (float*)(ws + 4u * 1024 * 1024);           // 32 KB
  int*            lab   = (int*)  (ws + 4u * 1024 * 1024 + 32 * 1024);
  float*          S_all = (float*)(ws + 4u * 1024 * 1024 + 64 * 1024);
  float*          S_pos = (float*)(ws + 4u * 1024 * 1024 + 96 * 1024);
  float*          out   = (float*)d_out;

  hipLaunchKernelGGL(milnce_prep, dim3(NROWS / 4), dim3(256), 0, stream,
                     feat, pos, labels, fb, inv_w, lab, S_all, S_pos);
  hipLaunchKernelGGL(milnce_gemm, dim3(NROWS / BN, NROWS / BM), dim3(256), 0, stream,
                     fb, inv_w, lab, S_all, S_pos);
  hipLaunchKernelGGL(milnce_final, dim3(1), dim3(1024), 0, stream,
                     S_all, S_pos, out);
}